// Round 7
// baseline (749.546 us; speedup 1.0000x reference)
//
#include <hip/hip_runtime.h>
#include <hip/hip_bf16.h>
#include <math.h>

#define T_TOK 2048
#define DIM   1024
#define NEXP  16
#define FDIM  512
#define TOPK  2

#define BM 128
#define BN 64
#define BK 32

typedef float f32x4 __attribute__((ext_vector_type(4)));
typedef short s16x8 __attribute__((ext_vector_type(8)));

static __device__ __forceinline__ ushort f2bf(float f) {
  union { float f; unsigned u; } v; v.f = f;
  unsigned u = v.u;
  unsigned r = u + 0x7fffu + ((u >> 16) & 1u);  // round-to-nearest-even
  return (ushort)(r >> 16);
}
static __device__ __forceinline__ float bf2f(ushort h) {
  union { unsigned u; float f; } v; v.u = ((unsigned)h) << 16; return v.f;
}
static __device__ __forceinline__ void split2(float f, ushort& h, ushort& l) {
  ushort hb = f2bf(f);
  h = hb;
  l = f2bf(f - bf2f(hb));
}

union u4s8 { uint4 u; s16x8 s; };
static __device__ __forceinline__ s16x8 as8(uint4 v) { u4s8 c; c.u = v; return c.s; }

// 8 fp32 -> bf16 hi-plane s16x8 + lo-plane s16x8 (in registers)
static __device__ __forceinline__ void conv8(float4 f0, float4 f1, s16x8& h, s16x8& l) {
  float fs[8] = {f0.x, f0.y, f0.z, f0.w, f1.x, f1.y, f1.z, f1.w};
  uint hp[4], lp[4];
#pragma unroll
  for (int j = 0; j < 4; ++j) {
    ushort ha, la, hb, lb;
    split2(fs[2 * j], ha, la);
    split2(fs[2 * j + 1], hb, lb);
    hp[j] = (uint)ha | ((uint)hb << 16);
    lp[j] = (uint)la | ((uint)lb << 16);
  }
  uint4 hu = make_uint4(hp[0], hp[1], hp[2], hp[3]);
  uint4 lu = make_uint4(lp[0], lp[1], lp[2], lp[3]);
  h = as8(hu); l = as8(lu);
}

// ---------------- Router: logits -> top-2 -> renormalized weights ----------
__global__ __launch_bounds__(64) void router_k(const float* __restrict__ x,
                                               const float* __restrict__ wg,
                                               int* __restrict__ sel,
                                               float* __restrict__ wt,
                                               int* __restrict__ cnt) {
  int t = blockIdx.x;
  int lane = threadIdx.x;
  const float* xr = x + (size_t)t * DIM;
  float acc[NEXP];
#pragma unroll
  for (int e = 0; e < NEXP; ++e) acc[e] = 0.f;
  for (int d0 = 0; d0 < DIM; d0 += 64) {
    float xv = xr[d0 + lane];
#pragma unroll
    for (int e = 0; e < NEXP; ++e) acc[e] += xv * wg[e * DIM + d0 + lane];
  }
#pragma unroll
  for (int e = 0; e < NEXP; ++e) {
    float v = acc[e];
    v += __shfl_xor(v, 32); v += __shfl_xor(v, 16); v += __shfl_xor(v, 8);
    v += __shfl_xor(v, 4);  v += __shfl_xor(v, 2);  v += __shfl_xor(v, 1);
    acc[e] = v;
  }
  if (lane == 0) {
    float b1 = -1e30f, b2 = -1e30f; int i1 = 0, i2 = 0;
#pragma unroll
    for (int e = 0; e < NEXP; ++e) {
      float v = acc[e];
      if (v > b1) { b2 = b1; i2 = i1; b1 = v; i1 = e; }
      else if (v > b2) { b2 = v; i2 = e; }
    }
    // NORM_TOPK: softmax denominator cancels -> w1 = 1/(1+exp(l2-l1))
    float r = expf(b2 - b1);
    float w2v = r / (1.f + r);
    float w1v = 1.f - w2v;
    sel[t * 2 + 0] = i1; sel[t * 2 + 1] = i2;
    wt[t * 2 + 0] = w1v; wt[t * 2 + 1] = w2v;
    atomicAdd(&cnt[i1], 1);
    atomicAdd(&cnt[i2], 1);
  }
}

// ---------------- X -> bf16 hi/lo planes -----------------------------------
__global__ __launch_bounds__(256) void xsplit_k(const float* __restrict__ x,
                                                ushort* __restrict__ xhi,
                                                ushort* __restrict__ xlo) {
  int idx = (blockIdx.x * 256 + threadIdx.x) * 4;
  float4 v = *(const float4*)(x + idx);
  ushort h0,h1,h2,h3,l0,l1,l2,l3;
  split2(v.x, h0, l0); split2(v.y, h1, l1);
  split2(v.z, h2, l2); split2(v.w, h3, l3);
  *(ushort4*)(xhi + idx) = make_ushort4(h0, h1, h2, h3);
  *(ushort4*)(xlo + idx) = make_ushort4(l0, l1, l2, l3);
}

// ---------------- exclusive prefix over expert counts ----------------------
__global__ void offsets_k(const int* __restrict__ cnt, int* __restrict__ off) {
  if (threadIdx.x == 0 && blockIdx.x == 0) {
    int s = 0;
#pragma unroll
    for (int e = 0; e < NEXP; ++e) { off[e] = s; s += cnt[e]; }
    off[NEXP] = s;  // == T_TOK*TOPK
  }
}

// ---------------- compact (token, weight) rows per expert ------------------
__global__ __launch_bounds__(256) void fill_k(const int* __restrict__ sel,
                                              const float* __restrict__ wt,
                                              const int* __restrict__ off,
                                              int* __restrict__ cnt2,
                                              int* __restrict__ rowtok,
                                              float* __restrict__ rowwt) {
  int i = blockIdx.x * 256 + threadIdx.x;
  if (i >= T_TOK * TOPK) return;
  int e = sel[i];
  int pos = off[e] + atomicAdd(&cnt2[e], 1);
  rowtok[pos] = i >> 1;
  rowwt[pos] = wt[i];
}

// ==== no-LDS direct-fragment GEMM machinery ================================
// MFMA 16x16x32 fragment = per lane 8 contiguous k-elems of one row -> load
// straight from global (16B dwordx4). No LDS, no barriers, waves independent.
// A (bf16 planes, L2-resident): 2-set pipeline. B (fp32 weights, HBM stream):
// 4-set pipeline (issue->consume ~3 steps >= HBM latency), converted to
// hi/lo bf16 in registers (split2, numerics identical to prior rounds).
#define DECL_SETS                                                            \
  uint4 aH00,aH10,aH20,aH30, aL00,aL10,aL20,aL30;                            \
  uint4 aH01,aH11,aH21,aH31, aL01,aL11,aL21,aL31;                            \
  float4 w000,w010,w100,w110;                                                \
  float4 w001,w011,w101,w111;                                                \
  float4 w002,w012,w102,w112;                                                \
  float4 w003,w013,w103,w113;

#define LOAD_A(S, KB) do { int kk = (KB); kk = kk <= AKMAX ? kk : AKMAX;     \
  aH0##S = *(const uint4*)(pAH[0] + kk); aH1##S = *(const uint4*)(pAH[1] + kk); \
  aH2##S = *(const uint4*)(pAH[2] + kk); aH3##S = *(const uint4*)(pAH[3] + kk); \
  aL0##S = *(const uint4*)(pAL[0] + kk); aL1##S = *(const uint4*)(pAL[1] + kk); \
  aL2##S = *(const uint4*)(pAL[2] + kk); aL3##S = *(const uint4*)(pAL[3] + kk); \
} while (0)

#define LOAD_B(S, KB) do { int kk = (KB); kk = kk <= AKMAX ? kk : AKMAX;     \
  w00##S = *(const float4*)(pB0 + kk); w01##S = *(const float4*)(pB0 + kk + 4); \
  w10##S = *(const float4*)(pB1 + kk); w11##S = *(const float4*)(pB1 + kk + 4); \
} while (0)

#define GSTEP(AS, BS, KS) do {                                               \
  s16x8 bh0, bl0, bh1, bl1;                                                  \
  conv8(w00##BS, w01##BS, bh0, bl0);                                         \
  conv8(w10##BS, w11##BS, bh1, bl1);                                         \
  LOAD_B(BS, ((KS) + 4) * BK);  /* B raw regs free after conv */             \
  s16x8 ah[4] = {as8(aH0##AS), as8(aH1##AS), as8(aH2##AS), as8(aH3##AS)};    \
  s16x8 al[4] = {as8(aL0##AS), as8(aL1##AS), as8(aL2##AS), as8(aL3##AS)};    \
  _Pragma("unroll")                                                          \
  for (int fm = 0; fm < 4; ++fm) {                                           \
    acc[fm][0] = __builtin_amdgcn_mfma_f32_16x16x32_bf16(ah[fm], bh0, acc[fm][0], 0, 0, 0); \
    acc[fm][0] = __builtin_amdgcn_mfma_f32_16x16x32_bf16(ah[fm], bl0, acc[fm][0], 0, 0, 0); \
    acc[fm][0] = __builtin_amdgcn_mfma_f32_16x16x32_bf16(al[fm], bh0, acc[fm][0], 0, 0, 0); \
    acc[fm][1] = __builtin_amdgcn_mfma_f32_16x16x32_bf16(ah[fm], bh1, acc[fm][1], 0, 0, 0); \
    acc[fm][1] = __builtin_amdgcn_mfma_f32_16x16x32_bf16(ah[fm], bl1, acc[fm][1], 0, 0, 0); \
    acc[fm][1] = __builtin_amdgcn_mfma_f32_16x16x32_bf16(al[fm], bl1 /*placeholder*/, acc[fm][1], 0, 0, 0); \
  }                                                                          \
  LOAD_A(AS, ((KS) + 2) * BK);  /* A regs free after MFMAs */                \
} while (0)

// NOTE: the placeholder above must be bh1 (al x bh term). Corrected macro:
#undef GSTEP
#define GSTEP(AS, BS, KS) do {                                               \
  s16x8 bh0, bl0, bh1, bl1;                                                  \
  conv8(w00##BS, w01##BS, bh0, bl0);                                         \
  conv8(w10##BS, w11##BS, bh1, bl1);                                         \
  LOAD_B(BS, ((KS) + 4) * BK);                                               \
  s16x8 ah[4] = {as8(aH0##AS), as8(aH1##AS), as8(aH2##AS), as8(aH3##AS)};    \
  s16x8 al[4] = {as8(aL0##AS), as8(aL1##AS), as8(aL2##AS), as8(aL3##AS)};    \
  _Pragma("unroll")                                                          \
  for (int fm = 0; fm < 4; ++fm) {                                           \
    acc[fm][0] = __builtin_amdgcn_mfma_f32_16x16x32_bf16(ah[fm], bh0, acc[fm][0], 0, 0, 0); \
    acc[fm][0] = __builtin_amdgcn_mfma_f32_16x16x32_bf16(ah[fm], bl0, acc[fm][0], 0, 0, 0); \
    acc[fm][0] = __builtin_amdgcn_mfma_f32_16x16x32_bf16(al[fm], bh0, acc[fm][0], 0, 0, 0); \
    acc[fm][1] = __builtin_amdgcn_mfma_f32_16x16x32_bf16(ah[fm], bh1, acc[fm][1], 0, 0, 0); \
    acc[fm][1] = __builtin_amdgcn_mfma_f32_16x16x32_bf16(ah[fm], bl1, acc[fm][1], 0, 0, 0); \
    acc[fm][1] = __builtin_amdgcn_mfma_f32_16x16x32_bf16(al[fm], bh1, acc[fm][1], 0, 0, 0); \
  }                                                                          \
  LOAD_A(AS, ((KS) + 2) * BK);                                               \
} while (0)

// ---------------- GEMM1: H[r][c] = sum_d X[tok(r)][d] * W13[e][c][d] -------
__global__ __launch_bounds__(256, 2) void gemm1_k(const ushort* __restrict__ xhi,
                                                  const ushort* __restrict__ xlo,
                                                  const float* __restrict__ w13,
                                                  const int* __restrict__ off,
                                                  const int* __restrict__ rowtok,
                                                  float* __restrict__ H) {
  enum { NS = DIM / BK, AKMAX = (NS - 1) * BK };
  int e = blockIdx.z;
  int rbeg = off[e];
  int rows = off[e + 1] - rbeg;
  int m0 = blockIdx.y * BM;
  if (m0 >= rows) return;
  int n0 = blockIdx.x * BN;

  int tid = threadIdx.x;
  int lane = tid & 63;
  int w = tid >> 6;
  int wm = (w & 1) * 64, wn = (w >> 1) * 32;
  int lr = lane & 15, lk = lane >> 4;

  const ushort* pAH[4]; const ushort* pAL[4];
#pragma unroll
  for (int fm = 0; fm < 4; ++fm) {
    int row = m0 + wm + fm * 16 + lr;
    row = row < rows ? row : rows - 1;
    int tok = rowtok[rbeg + row];
    size_t o = (size_t)tok * DIM + lk * 8;
    pAH[fm] = xhi + o; pAL[fm] = xlo + o;
  }
  const float* pB0 = w13 + ((size_t)e * (2 * FDIM) + (n0 + wn + lr)) * DIM + lk * 8;
  const float* pB1 = pB0 + (size_t)16 * DIM;

  f32x4 acc[4][2];
#pragma unroll
  for (int a = 0; a < 4; ++a)
#pragma unroll
    for (int b = 0; b < 2; ++b) acc[a][b] = {0.f, 0.f, 0.f, 0.f};

  DECL_SETS
  LOAD_A(0, 0); LOAD_A(1, BK);
  LOAD_B(0, 0); LOAD_B(1, BK); LOAD_B(2, 2 * BK); LOAD_B(3, 3 * BK);

  for (int ks = 0; ks < NS; ks += 4) {
    GSTEP(0, 0, ks);
    GSTEP(1, 1, ks + 1);
    GSTEP(0, 2, ks + 2);
    GSTEP(1, 3, ks + 3);
  }

  // epilogue: C/D layout col=lane&15, row=(lane>>4)*4+j  [m89/m91 verified]
#pragma unroll
  for (int fm = 0; fm < 4; ++fm) {
    int rloc = wm + fm * 16 + lk * 4;
#pragma unroll
    for (int j = 0; j < 4; ++j) {
      int row = rloc + j;
      if (m0 + row < rows) {
        size_t gr = (size_t)(rbeg + m0 + row) * (2 * FDIM);
#pragma unroll
        for (int fn = 0; fn < 2; ++fn)
          H[gr + n0 + wn + fn * 16 + lr] = acc[fm][fn][j];
      }
    }
  }
}

// ---------------- act = silu(gate)*up, stored as bf16 hi/lo ----------------
__global__ __launch_bounds__(256) void act_k(const float* __restrict__ H,
                                             ushort* __restrict__ ahi,
                                             ushort* __restrict__ alo) {
  int idx = (blockIdx.x * 256 + threadIdx.x) * 4;  // over 4096*512
  int r = idx >> 9;
  int f = idx & 511;
  const float* hrow = H + (size_t)r * (2 * FDIM);
  float4 g = *(const float4*)(hrow + f);
  float4 u = *(const float4*)(hrow + FDIM + f);
  float a0 = g.x / (1.f + expf(-g.x)) * u.x;
  float a1 = g.y / (1.f + expf(-g.y)) * u.y;
  float a2 = g.z / (1.f + expf(-g.z)) * u.z;
  float a3 = g.w / (1.f + expf(-g.w)) * u.w;
  ushort h0,h1,h2,h3,l0,l1,l2,l3;
  split2(a0, h0, l0); split2(a1, h1, l1);
  split2(a2, h2, l2); split2(a3, h3, l3);
  *(ushort4*)(ahi + (size_t)r * FDIM + f) = make_ushort4(h0, h1, h2, h3);
  *(ushort4*)(alo + (size_t)r * FDIM + f) = make_ushort4(l0, l1, l2, l3);
}

// ---------------- GEMM2: out[tok(r)][d] += w(r) * sum_f act[r][f]*W2[e][d][f]
__global__ __launch_bounds__(256, 2) void gemm2_k(const ushort* __restrict__ ahi,
                                                  const ushort* __restrict__ alo,
                                                  const float* __restrict__ w2,
                                                  const int* __restrict__ off,
                                                  const int* __restrict__ rowtok,
                                                  const float* __restrict__ rowwt,
                                                  float* __restrict__ out) {
  enum { NS = FDIM / BK, AKMAX = (NS - 1) * BK };
  int e = blockIdx.z;
  int rbeg = off[e];
  int rows = off[e + 1] - rbeg;
  int m0 = blockIdx.y * BM;
  if (m0 >= rows) return;
  int n0 = blockIdx.x * BN;

  int tid = threadIdx.x;
  int lane = tid & 63;
  int w = tid >> 6;
  int wm = (w & 1) * 64, wn = (w >> 1) * 32;
  int lr = lane & 15, lk = lane >> 4;

  const ushort* pAH[4]; const ushort* pAL[4];
#pragma unroll
  for (int fm = 0; fm < 4; ++fm) {
    int row = m0 + wm + fm * 16 + lr;
    row = row < rows ? row : rows - 1;
    size_t o = (size_t)(rbeg + row) * FDIM + lk * 8;
    pAH[fm] = ahi + o; pAL[fm] = alo + o;
  }
  const float* pB0 = w2 + ((size_t)e * DIM + (n0 + wn + lr)) * FDIM + lk * 8;
  const float* pB1 = pB0 + (size_t)16 * FDIM;

  f32x4 acc[4][2];
#pragma unroll
  for (int a = 0; a < 4; ++a)
#pragma unroll
    for (int b = 0; b < 2; ++b) acc[a][b] = {0.f, 0.f, 0.f, 0.f};

  DECL_SETS
  LOAD_A(0, 0); LOAD_A(1, BK);
  LOAD_B(0, 0); LOAD_B(1, BK); LOAD_B(2, 2 * BK); LOAD_B(3, 3 * BK);

  for (int ks = 0; ks < NS; ks += 4) {
    GSTEP(0, 0, ks);
    GSTEP(1, 1, ks + 1);
    GSTEP(0, 2, ks + 2);
    GSTEP(1, 3, ks + 3);
  }

#pragma unroll
  for (int fm = 0; fm < 4; ++fm) {
    int rloc = wm + fm * 16 + lk * 4;
#pragma unroll
    for (int j = 0; j < 4; ++j) {
      int row = rloc + j;
      if (m0 + row < rows) {
        int idx = rbeg + m0 + row;
        int tok = rowtok[idx];
        float wgt = rowwt[idx];
        float* orow = out + (size_t)tok * DIM + n0;
#pragma unroll
        for (int fn = 0; fn < 2; ++fn)
          atomicAdd(orow + wn + fn * 16 + lr, wgt * acc[fm][fn][j]);
      }
    }
  }
}

// ---------------------------------------------------------------------------
extern "C" void kernel_launch(void* const* d_in, const int* in_sizes, int n_in,
                              void* d_out, int out_size, void* d_ws, size_t ws_size,
                              hipStream_t stream) {
  const float* x   = (const float*)d_in[0];
  const float* wg  = (const float*)d_in[1];
  const float* w13 = (const float*)d_in[2];
  const float* w2  = (const float*)d_in[3];
  float* out = (float*)d_out;

  char* ws = (char*)d_ws;
  int*   cnt    = (int*)(ws + 0);
  int*   cnt2   = (int*)(ws + 64);
  int*   off    = (int*)(ws + 128);
  int*   sel    = (int*)(ws + 1024);
  float* wt     = (float*)(ws + 1024 + 16384);
  int*   rowtok = (int*)(ws + 1024 + 32768);
  float* rowwt  = (float*)(ws + 1024 + 49152);
  size_t o = 128 * 1024;
  ushort* xhi = (ushort*)(ws + o); o += (size_t)T_TOK * DIM * 2;
  ushort* xlo = (ushort*)(ws + o); o += (size_t)T_TOK * DIM * 2;
  float*  H   = (float*)(ws + o);  o += (size_t)T_TOK * TOPK * 2 * FDIM * 4;
  ushort* ahi = (ushort*)(ws + o); o += (size_t)T_TOK * TOPK * FDIM * 2;
  ushort* alo = (ushort*)(ws + o); o += (size_t)T_TOK * TOPK * FDIM * 2;
  // total ws use ≈ 32.1 MB

  hipMemsetAsync(ws, 0, 256, stream);                              // cnt, cnt2
  hipMemsetAsync(d_out, 0, (size_t)out_size * sizeof(float), stream);

  router_k<<<T_TOK, 64, 0, stream>>>(x, wg, sel, wt, cnt);
  xsplit_k<<<(T_TOK * DIM) / 1024, 256, 0, stream>>>(x, xhi, xlo);
  offsets_k<<<1, 64, 0, stream>>>(cnt, off);
  fill_k<<<(T_TOK * TOPK + 255) / 256, 256, 0, stream>>>(sel, wt, off, cnt2, rowtok, rowwt);

  dim3 g1(2 * FDIM / BN, T_TOK / BM, NEXP);  // (16,16,16), most blocks early-exit
  gemm1_k<<<g1, 256, 0, stream>>>(xhi, xlo, w13, off, rowtok, H);

  act_k<<<(T_TOK * TOPK * FDIM) / 1024, 256, 0, stream>>>(H, ahi, alo);

  dim3 g2(DIM / BN, T_TOK / BM, NEXP);       // (16,16,16)
  gemm2_k<<<g2, 256, 0, stream>>>(ahi, alo, w2, off, rowtok, rowwt, out);
}

// Round 8
// 295.173 us; speedup vs baseline: 2.5393x; 2.5393x over previous
//
#include <hip/hip_runtime.h>
#include <hip/hip_bf16.h>
#include <math.h>

#define T_TOK 2048
#define DIM   1024
#define NEXP  16
#define FDIM  512
#define TOPK  2

#define BM 128
#define BN 64
#define BK 32

typedef float f32x4 __attribute__((ext_vector_type(4)));
typedef short s16x8 __attribute__((ext_vector_type(8)));

static __device__ __forceinline__ ushort f2bf(float f) {
  union { float f; unsigned u; } v; v.f = f;
  unsigned u = v.u;
  unsigned r = u + 0x7fffu + ((u >> 16) & 1u);  // round-to-nearest-even
  return (ushort)(r >> 16);
}
static __device__ __forceinline__ float bf2f(ushort h) {
  union { unsigned u; float f; } v; v.u = ((unsigned)h) << 16; return v.f;
}
static __device__ __forceinline__ void split2(float f, ushort& h, ushort& l) {
  ushort hb = f2bf(f);
  h = hb;
  l = f2bf(f - bf2f(hb));
}

union u4s8 { uint4 u; s16x8 s; };
static __device__ __forceinline__ s16x8 as8(uint4 v) { u4s8 c; c.u = v; return c.s; }

// 8 fp32 -> bf16 hi-plane s16x8 + lo-plane s16x8 (in registers)
static __device__ __forceinline__ void conv8(float4 f0, float4 f1, s16x8& h, s16x8& l) {
  float fs[8] = {f0.x, f0.y, f0.z, f0.w, f1.x, f1.y, f1.z, f1.w};
  uint hp[4], lp[4];
#pragma unroll
  for (int j = 0; j < 4; ++j) {
    ushort ha, la, hb, lb;
    split2(fs[2 * j], ha, la);
    split2(fs[2 * j + 1], hb, lb);
    hp[j] = (uint)ha | ((uint)hb << 16);
    lp[j] = (uint)la | ((uint)lb << 16);
  }
  uint4 hu = make_uint4(hp[0], hp[1], hp[2], hp[3]);
  uint4 lu = make_uint4(lp[0], lp[1], lp[2], lp[3]);
  h = as8(hu); l = as8(lu);
}

// global -> LDS direct copy, 16B per lane. LDS dest = wave-uniform base +
// lane*16 (HW); global src is per-lane.
static __device__ __forceinline__ void gload16(const void* g, const void* l) {
  __builtin_amdgcn_global_load_lds(
      (const __attribute__((address_space(1))) void*)g,
      (__attribute__((address_space(3))) void*)l, 16, 0, 0);
}

// Swizzle for 64B-row tiles (A, bf16 [128][32]): f(q) = q ^ (((q>>6)&7)<<4).
// Bijective (crosses row-pairs via bit6); reader uses f(logical), stage
// source uses inv_swz64(linear dest) [m173 pre-swizzled-source pattern].
static __device__ __forceinline__ int inv_swz64(int p) {
  int q6 = ((p >> 6) ^ (p >> 8)) & 1;
  int q5 = ((p >> 5) ^ (p >> 7)) & 1;
  int q4 = ((p >> 4) ^ (p >> 6) ^ (p >> 8)) & 1;
  return (p & ~0x70) | (q4 << 4) | (q5 << 5) | (q6 << 6);
}

// ---------------- Router: logits -> top-2 -> renormalized weights ----------
__global__ __launch_bounds__(64) void router_k(const float* __restrict__ x,
                                               const float* __restrict__ wg,
                                               int* __restrict__ sel,
                                               float* __restrict__ wt,
                                               int* __restrict__ cnt) {
  int t = blockIdx.x;
  int lane = threadIdx.x;
  const float* xr = x + (size_t)t * DIM;
  float acc[NEXP];
#pragma unroll
  for (int e = 0; e < NEXP; ++e) acc[e] = 0.f;
  for (int d0 = 0; d0 < DIM; d0 += 64) {
    float xv = xr[d0 + lane];
#pragma unroll
    for (int e = 0; e < NEXP; ++e) acc[e] += xv * wg[e * DIM + d0 + lane];
  }
#pragma unroll
  for (int e = 0; e < NEXP; ++e) {
    float v = acc[e];
    v += __shfl_xor(v, 32); v += __shfl_xor(v, 16); v += __shfl_xor(v, 8);
    v += __shfl_xor(v, 4);  v += __shfl_xor(v, 2);  v += __shfl_xor(v, 1);
    acc[e] = v;
  }
  if (lane == 0) {
    float b1 = -1e30f, b2 = -1e30f; int i1 = 0, i2 = 0;
#pragma unroll
    for (int e = 0; e < NEXP; ++e) {
      float v = acc[e];
      if (v > b1) { b2 = b1; i2 = i1; b1 = v; i1 = e; }
      else if (v > b2) { b2 = v; i2 = e; }
    }
    // NORM_TOPK: softmax denominator cancels -> w1 = 1/(1+exp(l2-l1))
    float r = expf(b2 - b1);
    float w2v = r / (1.f + r);
    float w1v = 1.f - w2v;
    sel[t * 2 + 0] = i1; sel[t * 2 + 1] = i2;
    wt[t * 2 + 0] = w1v; wt[t * 2 + 1] = w2v;
    atomicAdd(&cnt[i1], 1);
    atomicAdd(&cnt[i2], 1);
  }
}

// ---------------- X -> bf16 hi/lo planes -----------------------------------
__global__ __launch_bounds__(256) void xsplit_k(const float* __restrict__ x,
                                                ushort* __restrict__ xhi,
                                                ushort* __restrict__ xlo) {
  int idx = (blockIdx.x * 256 + threadIdx.x) * 4;
  float4 v = *(const float4*)(x + idx);
  ushort h0,h1,h2,h3,l0,l1,l2,l3;
  split2(v.x, h0, l0); split2(v.y, h1, l1);
  split2(v.z, h2, l2); split2(v.w, h3, l3);
  *(ushort4*)(xhi + idx) = make_ushort4(h0, h1, h2, h3);
  *(ushort4*)(xlo + idx) = make_ushort4(l0, l1, l2, l3);
}

// ---------------- exclusive prefix over expert counts ----------------------
__global__ void offsets_k(const int* __restrict__ cnt, int* __restrict__ off) {
  if (threadIdx.x == 0 && blockIdx.x == 0) {
    int s = 0;
#pragma unroll
    for (int e = 0; e < NEXP; ++e) { off[e] = s; s += cnt[e]; }
    off[NEXP] = s;  // == T_TOK*TOPK
  }
}

// ---------------- compact (token, weight) rows per expert ------------------
__global__ __launch_bounds__(256) void fill_k(const int* __restrict__ sel,
                                              const float* __restrict__ wt,
                                              const int* __restrict__ off,
                                              int* __restrict__ cnt2,
                                              int* __restrict__ rowtok,
                                              float* __restrict__ rowwt) {
  int i = blockIdx.x * 256 + threadIdx.x;
  if (i >= T_TOK * TOPK) return;
  int e = sel[i];
  int pos = off[e] + atomicAdd(&cnt2[e], 1);
  rowtok[pos] = i >> 1;
  rowwt[pos] = wt[i];
}

// ==== 2-phase gload_lds double-buffer GEMM (T3 minimum template) ===========
// Per k-step: issue 6 global_load_lds into buf^1, ds_read+conv+24 MFMA on
// buf, then ONE vmcnt(0)+lgkmcnt(0)+s_barrier. Stage latency hides under the
// compute phase. No reg staging -> no spill risk (round-7 lesson). LDS
// swizzle via pre-swizzled global SOURCE + swizzled ds_read (rule #21).

#define MOE_STAGE(AhB, AlB, BfB, KB)                                         \
  do {                                                                       \
    gload16(gA00 + (KB), (const char*)(AhB) + ldsA0);                        \
    gload16(gA10 + (KB), (const char*)(AhB) + ldsA1);                        \
    gload16(gA01 + (KB), (const char*)(AlB) + ldsA0);                        \
    gload16(gA11 + (KB), (const char*)(AlB) + ldsA1);                        \
    gload16(gB0 + (KB), (const char*)(BfB) + ldsB0);                         \
    gload16(gB1 + (KB), (const char*)(BfB) + ldsB1);                         \
  } while (0)

#define MOE_COMPUTE(AhB, AlB, BfB)                                           \
  do {                                                                       \
    float4 br00 = *(const float4*)((const char*)(BfB) + boff00);             \
    float4 br01 = *(const float4*)((const char*)(BfB) + boff01);             \
    float4 br10 = *(const float4*)((const char*)(BfB) + boff10);             \
    float4 br11 = *(const float4*)((const char*)(BfB) + boff11);             \
    s16x8 bh0, bl0, bh1, bl1;                                                \
    conv8(br00, br01, bh0, bl0);                                             \
    conv8(br10, br11, bh1, bl1);                                             \
    _Pragma("unroll")                                                        \
    for (int fm = 0; fm < 4; ++fm) {                                         \
      s16x8 ah = *(const s16x8*)((const char*)(AhB) + aoff[fm]);             \
      s16x8 al = *(const s16x8*)((const char*)(AlB) + aoff[fm]);             \
      acc[fm][0] = __builtin_amdgcn_mfma_f32_16x16x32_bf16(ah, bh0, acc[fm][0], 0, 0, 0); \
      acc[fm][0] = __builtin_amdgcn_mfma_f32_16x16x32_bf16(ah, bl0, acc[fm][0], 0, 0, 0); \
      acc[fm][0] = __builtin_amdgcn_mfma_f32_16x16x32_bf16(al, bh0, acc[fm][0], 0, 0, 0); \
      acc[fm][1] = __builtin_amdgcn_mfma_f32_16x16x32_bf16(ah, bh1, acc[fm][1], 0, 0, 0); \
      acc[fm][1] = __builtin_amdgcn_mfma_f32_16x16x32_bf16(ah, bl1, acc[fm][1], 0, 0, 0); \
      acc[fm][1] = __builtin_amdgcn_mfma_f32_16x16x32_bf16(al, bh1, acc[fm][1], 0, 0, 0); \
    }                                                                        \
  } while (0)

#define MOE_SYNC()                                                           \
  do {                                                                       \
    asm volatile("s_waitcnt vmcnt(0) lgkmcnt(0)" ::: "memory");              \
    __builtin_amdgcn_s_barrier();                                            \
    __builtin_amdgcn_sched_barrier(0);                                       \
  } while (0)

// common per-lane setup for ds_read offsets (swizzled)
#define MOE_READ_OFFSETS()                                                   \
  int wm = (w & 1) * 64, wn = (w >> 1) * 32;                                 \
  int lr = lane & 15, lk = lane >> 4;                                        \
  int aoff[4];                                                               \
  _Pragma("unroll")                                                          \
  for (int fm = 0; fm < 4; ++fm) {                                           \
    int row = wm + fm * 16 + lr;                                             \
    aoff[fm] = (row * 64 + lk * 16) ^ ((row & 7) << 4);                      \
  }                                                                          \
  int brow0 = wn + 0 * 16 + lr, brow1 = wn + 1 * 16 + lr;                    \
  int boff00 = brow0 * 128 + ((lk * 32) ^ ((brow0 & 7) << 4));               \
  int boff01 = brow0 * 128 + (((lk * 32) + 16) ^ ((brow0 & 7) << 4));        \
  int boff10 = brow1 * 128 + ((lk * 32) ^ ((brow1 & 7) << 4));               \
  int boff11 = brow1 * 128 + (((lk * 32) + 16) ^ ((brow1 & 7) << 4));

// ---------------- GEMM1: H[r][c] = sum_d X[tok(r)][d] * W13[e][c][d] -------
__global__ __launch_bounds__(256, 4) void gemm1_k(const ushort* __restrict__ xhi,
                                                  const ushort* __restrict__ xlo,
                                                  const float* __restrict__ w13,
                                                  const int* __restrict__ off,
                                                  const int* __restrict__ rowtok,
                                                  float* __restrict__ H) {
  const int NS = DIM / BK;  // 32
  int e = blockIdx.z;
  int rbeg = off[e];
  int rows = off[e + 1] - rbeg;
  int m0 = blockIdx.y * BM;
  if (m0 >= rows) return;
  int n0 = blockIdx.x * BN;

  __shared__ ushort Ah[2][BM * BK];  // [128][32] bf16, swizzled, 8KB/buf
  __shared__ ushort Al[2][BM * BK];
  __shared__ float  Bf[2][BN * BK];  // [64][32] fp32, swizzled, 8KB/buf

  int tid = threadIdx.x;
  int lane = tid & 63;
  int w = tid >> 6;

  // stage pointers: linear LDS dest p -> logical q -> per-lane global src
  int ldsA0 = w * 2048, ldsA1 = w * 2048 + 1024;
  int ldsB0 = ldsA0, ldsB1 = ldsA1;
  const ushort *gA00, *gA10, *gA01, *gA11;
  {
    int p0 = ldsA0 + lane * 16, p1 = ldsA1 + lane * 16;
    int q0 = inv_swz64(p0), q1 = inv_swz64(p1);
    int r0 = m0 + (q0 >> 6); r0 = r0 < rows ? r0 : rows - 1;
    int r1 = m0 + (q1 >> 6); r1 = r1 < rows ? r1 : rows - 1;
    size_t b0 = (size_t)rowtok[rbeg + r0] * DIM + ((q0 & 63) >> 1);
    size_t b1 = (size_t)rowtok[rbeg + r1] * DIM + ((q1 & 63) >> 1);
    gA00 = xhi + b0; gA10 = xhi + b1;
    gA01 = xlo + b0; gA11 = xlo + b1;
  }
  const float *gB0, *gB1;
  {
    int p0 = ldsB0 + lane * 16, p1 = ldsB1 + lane * 16;
    int r0 = p0 >> 7, r1 = p1 >> 7;
    int c0 = ((p0 & 127) ^ ((r0 & 7) << 4)) >> 2;
    int c1 = ((p1 & 127) ^ ((r1 & 7) << 4)) >> 2;
    gB0 = w13 + ((size_t)e * (2 * FDIM) + (n0 + r0)) * DIM + c0;
    gB1 = w13 + ((size_t)e * (2 * FDIM) + (n0 + r1)) * DIM + c1;
  }

  MOE_READ_OFFSETS()

  f32x4 acc[4][2];
#pragma unroll
  for (int a = 0; a < 4; ++a)
#pragma unroll
    for (int b = 0; b < 2; ++b) acc[a][b] = {0.f, 0.f, 0.f, 0.f};

  MOE_STAGE(Ah[0], Al[0], Bf[0], 0);
  MOE_SYNC();

#pragma unroll 2
  for (int ks = 0; ks < NS; ++ks) {
    int cur = ks & 1;
    if (ks + 1 < NS) {
      if (cur == 0) MOE_STAGE(Ah[1], Al[1], Bf[1], (ks + 1) * BK);
      else          MOE_STAGE(Ah[0], Al[0], Bf[0], (ks + 1) * BK);
    }
    if (cur == 0) MOE_COMPUTE(Ah[0], Al[0], Bf[0]);
    else          MOE_COMPUTE(Ah[1], Al[1], Bf[1]);
    MOE_SYNC();
  }

  // epilogue: C/D layout col=lane&15, row=(lane>>4)*4+j  [m89/m91 verified]
#pragma unroll
  for (int fm = 0; fm < 4; ++fm) {
    int rloc = wm + fm * 16 + lk * 4;
#pragma unroll
    for (int j = 0; j < 4; ++j) {
      int row = rloc + j;
      if (m0 + row < rows) {
        size_t gr = (size_t)(rbeg + m0 + row) * (2 * FDIM);
#pragma unroll
        for (int fn = 0; fn < 2; ++fn)
          H[gr + n0 + wn + fn * 16 + lr] = acc[fm][fn][j];
      }
    }
  }
}

// ---------------- act = silu(gate)*up, stored as bf16 hi/lo ----------------
__global__ __launch_bounds__(256) void act_k(const float* __restrict__ H,
                                             ushort* __restrict__ ahi,
                                             ushort* __restrict__ alo) {
  int idx = (blockIdx.x * 256 + threadIdx.x) * 4;  // over 4096*512
  int r = idx >> 9;
  int f = idx & 511;
  const float* hrow = H + (size_t)r * (2 * FDIM);
  float4 g = *(const float4*)(hrow + f);
  float4 u = *(const float4*)(hrow + FDIM + f);
  float a0 = g.x / (1.f + expf(-g.x)) * u.x;
  float a1 = g.y / (1.f + expf(-g.y)) * u.y;
  float a2 = g.z / (1.f + expf(-g.z)) * u.z;
  float a3 = g.w / (1.f + expf(-g.w)) * u.w;
  ushort h0,h1,h2,h3,l0,l1,l2,l3;
  split2(a0, h0, l0); split2(a1, h1, l1);
  split2(a2, h2, l2); split2(a3, h3, l3);
  *(ushort4*)(ahi + (size_t)r * FDIM + f) = make_ushort4(h0, h1, h2, h3);
  *(ushort4*)(alo + (size_t)r * FDIM + f) = make_ushort4(l0, l1, l2, l3);
}

// ---------------- GEMM2: out[tok(r)][d] += w(r) * sum_f act[r][f]*W2[e][d][f]
__global__ __launch_bounds__(256, 4) void gemm2_k(const ushort* __restrict__ ahi,
                                                  const ushort* __restrict__ alo,
                                                  const float* __restrict__ w2,
                                                  const int* __restrict__ off,
                                                  const int* __restrict__ rowtok,
                                                  const float* __restrict__ rowwt,
                                                  float* __restrict__ out) {
  const int NS = FDIM / BK;  // 16
  int e = blockIdx.z;
  int rbeg = off[e];
  int rows = off[e + 1] - rbeg;
  int m0 = blockIdx.y * BM;
  if (m0 >= rows) return;
  int n0 = blockIdx.x * BN;

  __shared__ ushort Ah[2][BM * BK];
  __shared__ ushort Al[2][BM * BK];
  __shared__ float  Bf[2][BN * BK];

  int tid = threadIdx.x;
  int lane = tid & 63;
  int w = tid >> 6;

  int ldsA0 = w * 2048, ldsA1 = w * 2048 + 1024;
  int ldsB0 = ldsA0, ldsB1 = ldsA1;
  const ushort *gA00, *gA10, *gA01, *gA11;
  {
    int p0 = ldsA0 + lane * 16, p1 = ldsA1 + lane * 16;
    int q0 = inv_swz64(p0), q1 = inv_swz64(p1);
    int r0 = m0 + (q0 >> 6); r0 = r0 < rows ? r0 : rows - 1;
    int r1 = m0 + (q1 >> 6); r1 = r1 < rows ? r1 : rows - 1;
    size_t b0 = (size_t)(rbeg + r0) * FDIM + ((q0 & 63) >> 1);
    size_t b1 = (size_t)(rbeg + r1) * FDIM + ((q1 & 63) >> 1);
    gA00 = ahi + b0; gA10 = ahi + b1;
    gA01 = alo + b0; gA11 = alo + b1;
  }
  const float *gB0, *gB1;
  {
    int p0 = ldsB0 + lane * 16, p1 = ldsB1 + lane * 16;
    int r0 = p0 >> 7, r1 = p1 >> 7;
    int c0 = ((p0 & 127) ^ ((r0 & 7) << 4)) >> 2;
    int c1 = ((p1 & 127) ^ ((r1 & 7) << 4)) >> 2;
    gB0 = w2 + ((size_t)e * DIM + (n0 + r0)) * FDIM + c0;
    gB1 = w2 + ((size_t)e * DIM + (n0 + r1)) * FDIM + c1;
  }

  MOE_READ_OFFSETS()

  f32x4 acc[4][2];
#pragma unroll
  for (int a = 0; a < 4; ++a)
#pragma unroll
    for (int b = 0; b < 2; ++b) acc[a][b] = {0.f, 0.f, 0.f, 0.f};

  MOE_STAGE(Ah[0], Al[0], Bf[0], 0);
  MOE_SYNC();

#pragma unroll 2
  for (int ks = 0; ks < NS; ++ks) {
    int cur = ks & 1;
    if (ks + 1 < NS) {
      if (cur == 0) MOE_STAGE(Ah[1], Al[1], Bf[1], (ks + 1) * BK);
      else          MOE_STAGE(Ah[0], Al[0], Bf[0], (ks + 1) * BK);
    }
    if (cur == 0) MOE_COMPUTE(Ah[0], Al[0], Bf[0]);
    else          MOE_COMPUTE(Ah[1], Al[1], Bf[1]);
    MOE_SYNC();
  }

#pragma unroll
  for (int fm = 0; fm < 4; ++fm) {
    int rloc = wm + fm * 16 + lk * 4;
#pragma unroll
    for (int j = 0; j < 4; ++j) {
      int row = rloc + j;
      if (m0 + row < rows) {
        int idx = rbeg + m0 + row;
        int tok = rowtok[idx];
        float wgt = rowwt[idx];
        float* orow = out + (size_t)tok * DIM + n0;
#pragma unroll
        for (int fn = 0; fn < 2; ++fn)
          atomicAdd(orow + wn + fn * 16 + lr, wgt * acc[fm][fn][j]);
      }
    }
  }
}

// ---------------------------------------------------------------------------
extern "C" void kernel_launch(void* const* d_in, const int* in_sizes, int n_in,
                              void* d_out, int out_size, void* d_ws, size_t ws_size,
                              hipStream_t stream) {
  const float* x   = (const float*)d_in[0];
  const float* wg  = (const float*)d_in[1];
  const float* w13 = (const float*)d_in[2];
  const float* w2  = (const float*)d_in[3];
  float* out = (float*)d_out;

  char* ws = (char*)d_ws;
  int*   cnt    = (int*)(ws + 0);
  int*   cnt2   = (int*)(ws + 64);
  int*   off    = (int*)(ws + 128);
  int*   sel    = (int*)(ws + 1024);
  float* wt     = (float*)(ws + 1024 + 16384);
  int*   rowtok = (int*)(ws + 1024 + 32768);
  float* rowwt  = (float*)(ws + 1024 + 49152);
  size_t o = 128 * 1024;
  ushort* xhi = (ushort*)(ws + o); o += (size_t)T_TOK * DIM * 2;
  ushort* xlo = (ushort*)(ws + o); o += (size_t)T_TOK * DIM * 2;
  float*  H   = (float*)(ws + o);  o += (size_t)T_TOK * TOPK * 2 * FDIM * 4;
  ushort* ahi = (ushort*)(ws + o); o += (size_t)T_TOK * TOPK * FDIM * 2;
  ushort* alo = (ushort*)(ws + o); o += (size_t)T_TOK * TOPK * FDIM * 2;
  // total ws use ≈ 32.1 MB

  hipMemsetAsync(ws, 0, 256, stream);                              // cnt, cnt2
  hipMemsetAsync(d_out, 0, (size_t)out_size * sizeof(float), stream);

  router_k<<<T_TOK, 64, 0, stream>>>(x, wg, sel, wt, cnt);
  xsplit_k<<<(T_TOK * DIM) / 1024, 256, 0, stream>>>(x, xhi, xlo);
  offsets_k<<<1, 64, 0, stream>>>(cnt, off);
  fill_k<<<(T_TOK * TOPK + 255) / 256, 256, 0, stream>>>(sel, wt, off, cnt2, rowtok, rowwt);

  dim3 g1(2 * FDIM / BN, T_TOK / BM, NEXP);  // (16,16,16), most blocks early-exit
  gemm1_k<<<g1, 256, 0, stream>>>(xhi, xlo, w13, off, rowtok, H);

  act_k<<<(T_TOK * TOPK * FDIM) / 1024, 256, 0, stream>>>(H, ahi, alo);

  dim3 g2(DIM / BN, T_TOK / BM, NEXP);       // (16,16,16)
  gemm2_k<<<g2, 256, 0, stream>>>(ahi, alo, w2, off, rowtok, rowwt, out);
}

// Round 9
// 292.792 us; speedup vs baseline: 2.5600x; 1.0081x over previous
//
#include <hip/hip_runtime.h>
#include <hip/hip_bf16.h>
#include <math.h>

#define T_TOK 2048
#define DIM   1024
#define NEXP  16
#define FDIM  512
#define TOPK  2

#define BM 128
#define BN 64
#define BK 32

typedef float f32x4 __attribute__((ext_vector_type(4)));
typedef short s16x8 __attribute__((ext_vector_type(8)));

static __device__ __forceinline__ ushort f2bf(float f) {
  union { float f; unsigned u; } v; v.f = f;
  unsigned u = v.u;
  unsigned r = u + 0x7fffu + ((u >> 16) & 1u);  // round-to-nearest-even
  return (ushort)(r >> 16);
}
static __device__ __forceinline__ float bf2f(ushort h) {
  union { unsigned u; float f; } v; v.u = ((unsigned)h) << 16; return v.f;
}
static __device__ __forceinline__ void split2(float f, ushort& h, ushort& l) {
  ushort hb = f2bf(f);
  h = hb;
  l = f2bf(f - bf2f(hb));
}

union u4s8 { uint4 u; s16x8 s; };
static __device__ __forceinline__ s16x8 as8(uint4 v) { u4s8 c; c.u = v; return c.s; }

// 8 fp32 -> bf16 hi-plane s16x8 + lo-plane s16x8 (in registers)
static __device__ __forceinline__ void conv8(float4 f0, float4 f1, s16x8& h, s16x8& l) {
  float fs[8] = {f0.x, f0.y, f0.z, f0.w, f1.x, f1.y, f1.z, f1.w};
  uint hp[4], lp[4];
#pragma unroll
  for (int j = 0; j < 4; ++j) {
    ushort ha, la, hb, lb;
    split2(fs[2 * j], ha, la);
    split2(fs[2 * j + 1], hb, lb);
    hp[j] = (uint)ha | ((uint)hb << 16);
    lp[j] = (uint)la | ((uint)lb << 16);
  }
  uint4 hu = make_uint4(hp[0], hp[1], hp[2], hp[3]);
  uint4 lu = make_uint4(lp[0], lp[1], lp[2], lp[3]);
  h = as8(hu); l = as8(lu);
}

// global -> LDS direct copy, 16B per lane.
static __device__ __forceinline__ void gload16(const void* g, const void* l) {
  __builtin_amdgcn_global_load_lds(
      (const __attribute__((address_space(1))) void*)g,
      (__attribute__((address_space(3))) void*)l, 16, 0, 0);
}

// Swizzle for 64B-row tiles (A, bf16 [128][32]): f(q) = q ^ (((q>>6)&7)<<4).
static __device__ __forceinline__ int inv_swz64(int p) {
  int q6 = ((p >> 6) ^ (p >> 8)) & 1;
  int q5 = ((p >> 5) ^ (p >> 7)) & 1;
  int q4 = ((p >> 4) ^ (p >> 6) ^ (p >> 8)) & 1;
  return (p & ~0x70) | (q4 << 4) | (q5 << 5) | (q6 << 6);
}

// ---------------- Router: logits -> top-2 -> renormalized weights ----------
// (atomics removed -> counts now from hist_k; Guideline 12)
__global__ __launch_bounds__(64) void router_k(const float* __restrict__ x,
                                               const float* __restrict__ wg,
                                               int* __restrict__ sel,
                                               float* __restrict__ wt) {
  int t = blockIdx.x;
  int lane = threadIdx.x;
  const float* xr = x + (size_t)t * DIM;
  float acc[NEXP];
#pragma unroll
  for (int e = 0; e < NEXP; ++e) acc[e] = 0.f;
  for (int d0 = 0; d0 < DIM; d0 += 64) {
    float xv = xr[d0 + lane];
#pragma unroll
    for (int e = 0; e < NEXP; ++e) acc[e] += xv * wg[e * DIM + d0 + lane];
  }
#pragma unroll
  for (int e = 0; e < NEXP; ++e) {
    float v = acc[e];
    v += __shfl_xor(v, 32); v += __shfl_xor(v, 16); v += __shfl_xor(v, 8);
    v += __shfl_xor(v, 4);  v += __shfl_xor(v, 2);  v += __shfl_xor(v, 1);
    acc[e] = v;
  }
  if (lane == 0) {
    float b1 = -1e30f, b2 = -1e30f; int i1 = 0, i2 = 0;
#pragma unroll
    for (int e = 0; e < NEXP; ++e) {
      float v = acc[e];
      if (v > b1) { b2 = b1; i2 = i1; b1 = v; i1 = e; }
      else if (v > b2) { b2 = v; i2 = e; }
    }
    // NORM_TOPK: softmax denominator cancels -> w1 = 1/(1+exp(l2-l1))
    float r = expf(b2 - b1);
    float w2v = r / (1.f + r);
    float w1v = 1.f - w2v;
    sel[t * 2 + 0] = i1; sel[t * 2 + 1] = i2;
    wt[t * 2 + 0] = w1v; wt[t * 2 + 1] = w2v;
  }
}

// ---------------- X -> bf16 hi/lo planes -----------------------------------
__global__ __launch_bounds__(256) void xsplit_k(const float* __restrict__ x,
                                                ushort* __restrict__ xhi,
                                                ushort* __restrict__ xlo) {
  int idx = (blockIdx.x * 256 + threadIdx.x) * 4;
  float4 v = *(const float4*)(x + idx);
  ushort h0,h1,h2,h3,l0,l1,l2,l3;
  split2(v.x, h0, l0); split2(v.y, h1, l1);
  split2(v.z, h2, l2); split2(v.w, h3, l3);
  *(ushort4*)(xhi + idx) = make_ushort4(h0, h1, h2, h3);
  *(ushort4*)(xlo + idx) = make_ushort4(l0, l1, l2, l3);
}

// ---------------- expert histogram (LDS-aggregated, 256 global atomics) ----
__global__ __launch_bounds__(256) void hist_k(const int* __restrict__ sel,
                                              int* __restrict__ cnt) {
  __shared__ int h[NEXP];
  int tid = threadIdx.x;
  if (tid < NEXP) h[tid] = 0;
  __syncthreads();
  int i = blockIdx.x * 256 + tid;  // grid exactly covers T_TOK*TOPK
  atomicAdd(&h[sel[i]], 1);
  __syncthreads();
  if (tid < NEXP) atomicAdd(&cnt[tid], h[tid]);
}

// ---------------- exclusive prefix over expert counts ----------------------
__global__ void offsets_k(const int* __restrict__ cnt, int* __restrict__ off) {
  if (threadIdx.x == 0 && blockIdx.x == 0) {
    int s = 0;
#pragma unroll
    for (int e = 0; e < NEXP; ++e) { off[e] = s; s += cnt[e]; }
    off[NEXP] = s;  // == T_TOK*TOPK
  }
}

// ---------------- compact rows per expert (two-level, low contention) ------
__global__ __launch_bounds__(256) void fill_k(const int* __restrict__ sel,
                                              const float* __restrict__ wt,
                                              const int* __restrict__ off,
                                              int* __restrict__ cnt2,
                                              int* __restrict__ rowtok,
                                              float* __restrict__ rowwt) {
  __shared__ int h[NEXP];
  __shared__ int base[NEXP];
  int tid = threadIdx.x;
  if (tid < NEXP) h[tid] = 0;
  __syncthreads();
  int i = blockIdx.x * 256 + tid;  // grid exactly covers T_TOK*TOPK
  int e = sel[i];
  int lrank = atomicAdd(&h[e], 1);          // LDS atomic (fast)
  __syncthreads();
  if (tid < NEXP) base[tid] = atomicAdd(&cnt2[tid], h[tid]);  // 16/block global
  __syncthreads();
  int pos = off[e] + base[e] + lrank;
  rowtok[pos] = i >> 1;
  rowwt[pos] = wt[i];
}

// ==== counted-vmcnt 2-stream pipelined GEMM (T3+T4) ========================
// A (L2-resident token planes): 2-buffer, staged 1 step ahead.
// B (HBM weight stream): 3-buffer, staged 2 steps ahead.
// Per steady step: issue A(ks+1) [4 loads] then B(ks+2) [2 loads];
// end-of-step wait = vmcnt(2) (completes A(ks+1)+B(ks+1), leaves B(ks+2)
// in flight) -> vmcnt NEVER drains to 0 in the main loop [T4, m218].
#define MOE_STAGE_A(AhB, AlB, KB)                                            \
  do {                                                                       \
    gload16(gA00 + (KB), (const char*)(AhB) + ldsA0);                        \
    gload16(gA10 + (KB), (const char*)(AhB) + ldsA1);                        \
    gload16(gA01 + (KB), (const char*)(AlB) + ldsA0);                        \
    gload16(gA11 + (KB), (const char*)(AlB) + ldsA1);                        \
  } while (0)

#define MOE_STAGE_B(BfB, KB)                                                 \
  do {                                                                       \
    gload16(gB0 + (KB), (const char*)(BfB) + ldsB0);                         \
    gload16(gB1 + (KB), (const char*)(BfB) + ldsB1);                         \
  } while (0)

#define MOE_COMPUTE(AhB, AlB, BfB)                                           \
  do {                                                                       \
    float4 br00 = *(const float4*)((const char*)(BfB) + boff00);             \
    float4 br01 = *(const float4*)((const char*)(BfB) + boff01);             \
    float4 br10 = *(const float4*)((const char*)(BfB) + boff10);             \
    float4 br11 = *(const float4*)((const char*)(BfB) + boff11);             \
    s16x8 bh0, bl0, bh1, bl1;                                                \
    conv8(br00, br01, bh0, bl0);                                             \
    conv8(br10, br11, bh1, bl1);                                             \
    _Pragma("unroll")                                                        \
    for (int fm = 0; fm < 4; ++fm) {                                         \
      s16x8 ah = *(const s16x8*)((const char*)(AhB) + aoff[fm]);             \
      s16x8 al = *(const s16x8*)((const char*)(AlB) + aoff[fm]);             \
      acc[fm][0] = __builtin_amdgcn_mfma_f32_16x16x32_bf16(ah, bh0, acc[fm][0], 0, 0, 0); \
      acc[fm][0] = __builtin_amdgcn_mfma_f32_16x16x32_bf16(ah, bl0, acc[fm][0], 0, 0, 0); \
      acc[fm][0] = __builtin_amdgcn_mfma_f32_16x16x32_bf16(al, bh0, acc[fm][0], 0, 0, 0); \
      acc[fm][1] = __builtin_amdgcn_mfma_f32_16x16x32_bf16(ah, bh1, acc[fm][1], 0, 0, 0); \
      acc[fm][1] = __builtin_amdgcn_mfma_f32_16x16x32_bf16(ah, bl1, acc[fm][1], 0, 0, 0); \
      acc[fm][1] = __builtin_amdgcn_mfma_f32_16x16x32_bf16(al, bh1, acc[fm][1], 0, 0, 0); \
    }                                                                        \
  } while (0)

#define MOE_BAR()                                                            \
  do { __builtin_amdgcn_s_barrier(); __builtin_amdgcn_sched_barrier(0); } while (0)

// main loop body (steady state): NS >= 3 required (32 and 16 both ok)
#define MOE_PIPE_LOOP(NSv)                                                   \
  do {                                                                       \
    MOE_STAGE_A(ahc, alc, 0);                                                \
    MOE_STAGE_B(bfc, 0);                                                     \
    MOE_STAGE_B(bf1, BK);                                                    \
    asm volatile("s_waitcnt vmcnt(2)" ::: "memory");                         \
    MOE_BAR();                                                               \
    _Pragma("unroll 1")                                                      \
    for (int ks = 0; ks < (NSv) - 2; ++ks) {                                 \
      MOE_STAGE_A(ahn, aln, (ks + 1) * BK);                                  \
      MOE_STAGE_B(bfn, (ks + 2) * BK);                                       \
      MOE_COMPUTE(ahc, alc, bfc);                                            \
      asm volatile("s_waitcnt vmcnt(2) lgkmcnt(0)" ::: "memory");            \
      MOE_BAR();                                                             \
      { ushort* t = ahc; ahc = ahn; ahn = t; }                               \
      { ushort* t = alc; alc = aln; aln = t; }                               \
      { float* t = bfc; bfc = bf1; bf1 = bfn; bfn = t; }                     \
    }                                                                        \
    MOE_STAGE_A(ahn, aln, ((NSv) - 1) * BK);                                 \
    MOE_COMPUTE(ahc, alc, bfc);                                              \
    asm volatile("s_waitcnt vmcnt(0) lgkmcnt(0)" ::: "memory");              \
    MOE_BAR();                                                               \
    MOE_COMPUTE(ahn, aln, bf1);                                              \
  } while (0)

// common per-lane ds_read offsets (swizzled) — identical to round 8
#define MOE_READ_OFFSETS()                                                   \
  int wm = (w & 1) * 64, wn = (w >> 1) * 32;                                 \
  int lr = lane & 15, lk = lane >> 4;                                        \
  int aoff[4];                                                               \
  _Pragma("unroll")                                                          \
  for (int fm = 0; fm < 4; ++fm) {                                           \
    int row = wm + fm * 16 + lr;                                             \
    aoff[fm] = (row * 64 + lk * 16) ^ ((row & 7) << 4);                      \
  }                                                                          \
  int brow0 = wn + 0 * 16 + lr, brow1 = wn + 1 * 16 + lr;                    \
  int boff00 = brow0 * 128 + ((lk * 32) ^ ((brow0 & 7) << 4));               \
  int boff01 = brow0 * 128 + (((lk * 32) + 16) ^ ((brow0 & 7) << 4));        \
  int boff10 = brow1 * 128 + ((lk * 32) ^ ((brow1 & 7) << 4));               \
  int boff11 = brow1 * 128 + (((lk * 32) + 16) ^ ((brow1 & 7) << 4));

// ---------------- GEMM1: H[r][c] = sum_d X[tok(r)][d] * W13[e][c][d] -------
__global__ __launch_bounds__(256, 2) void gemm1_k(const ushort* __restrict__ xhi,
                                                  const ushort* __restrict__ xlo,
                                                  const float* __restrict__ w13,
                                                  const int* __restrict__ off,
                                                  const int* __restrict__ rowtok,
                                                  float* __restrict__ H) {
  const int NS = DIM / BK;  // 32
  int e = blockIdx.z;
  int rbeg = off[e];
  int rows = off[e + 1] - rbeg;
  int m0 = blockIdx.y * BM;
  if (m0 >= rows) return;
  int n0 = blockIdx.x * BN;

  __shared__ ushort Ah[2][BM * BK];  // 8KB/buf, swizzled 64B rows
  __shared__ ushort Al[2][BM * BK];
  __shared__ float  Bf[3][BN * BK];  // 8KB/buf, swizzled 128B rows

  int tid = threadIdx.x;
  int lane = tid & 63;
  int w = tid >> 6;

  int ldsA0 = w * 2048, ldsA1 = w * 2048 + 1024;
  int ldsB0 = ldsA0, ldsB1 = ldsA1;
  const ushort *gA00, *gA10, *gA01, *gA11;
  {
    int p0 = ldsA0 + lane * 16, p1 = ldsA1 + lane * 16;
    int q0 = inv_swz64(p0), q1 = inv_swz64(p1);
    int r0 = m0 + (q0 >> 6); r0 = r0 < rows ? r0 : rows - 1;
    int r1 = m0 + (q1 >> 6); r1 = r1 < rows ? r1 : rows - 1;
    size_t b0 = (size_t)rowtok[rbeg + r0] * DIM + ((q0 & 63) >> 1);
    size_t b1 = (size_t)rowtok[rbeg + r1] * DIM + ((q1 & 63) >> 1);
    gA00 = xhi + b0; gA10 = xhi + b1;
    gA01 = xlo + b0; gA11 = xlo + b1;
  }
  const float *gB0, *gB1;
  {
    int p0 = ldsB0 + lane * 16, p1 = ldsB1 + lane * 16;
    int r0 = p0 >> 7, r1 = p1 >> 7;
    int c0 = ((p0 & 127) ^ ((r0 & 7) << 4)) >> 2;
    int c1 = ((p1 & 127) ^ ((r1 & 7) << 4)) >> 2;
    gB0 = w13 + ((size_t)e * (2 * FDIM) + (n0 + r0)) * DIM + c0;
    gB1 = w13 + ((size_t)e * (2 * FDIM) + (n0 + r1)) * DIM + c1;
  }

  MOE_READ_OFFSETS()

  f32x4 acc[4][2];
#pragma unroll
  for (int a = 0; a < 4; ++a)
#pragma unroll
    for (int b = 0; b < 2; ++b) acc[a][b] = {0.f, 0.f, 0.f, 0.f};

  ushort *ahc = Ah[0], *ahn = Ah[1];
  ushort *alc = Al[0], *aln = Al[1];
  float  *bfc = Bf[0], *bf1 = Bf[1], *bfn = Bf[2];

  MOE_PIPE_LOOP(NS);

  // epilogue: C/D layout col=lane&15, row=(lane>>4)*4+j  [m89/m91 verified]
#pragma unroll
  for (int fm = 0; fm < 4; ++fm) {
    int rloc = wm + fm * 16 + lk * 4;
#pragma unroll
    for (int j = 0; j < 4; ++j) {
      int row = rloc + j;
      if (m0 + row < rows) {
        size_t gr = (size_t)(rbeg + m0 + row) * (2 * FDIM);
#pragma unroll
        for (int fn = 0; fn < 2; ++fn)
          H[gr + n0 + wn + fn * 16 + lr] = acc[fm][fn][j];
      }
    }
  }
}

// ---------------- act = silu(gate)*up, stored as bf16 hi/lo ----------------
__global__ __launch_bounds__(256) void act_k(const float* __restrict__ H,
                                             ushort* __restrict__ ahi,
                                             ushort* __restrict__ alo) {
  int idx = (blockIdx.x * 256 + threadIdx.x) * 4;  // over 4096*512
  int r = idx >> 9;
  int f = idx & 511;
  const float* hrow = H + (size_t)r * (2 * FDIM);
  float4 g = *(const float4*)(hrow + f);
  float4 u = *(const float4*)(hrow + FDIM + f);
  float a0 = g.x / (1.f + expf(-g.x)) * u.x;
  float a1 = g.y / (1.f + expf(-g.y)) * u.y;
  float a2 = g.z / (1.f + expf(-g.z)) * u.z;
  float a3 = g.w / (1.f + expf(-g.w)) * u.w;
  ushort h0,h1,h2,h3,l0,l1,l2,l3;
  split2(a0, h0, l0); split2(a1, h1, l1);
  split2(a2, h2, l2); split2(a3, h3, l3);
  *(ushort4*)(ahi + (size_t)r * FDIM + f) = make_ushort4(h0, h1, h2, h3);
  *(ushort4*)(alo + (size_t)r * FDIM + f) = make_ushort4(l0, l1, l2, l3);
}

// ---------------- GEMM2: out[tok(r)][d] += w(r) * sum_f act[r][f]*W2[e][d][f]
__global__ __launch_bounds__(256, 2) void gemm2_k(const ushort* __restrict__ ahi,
                                                  const ushort* __restrict__ alo,
                                                  const float* __restrict__ w2,
                                                  const int* __restrict__ off,
                                                  const int* __restrict__ rowtok,
                                                  const float* __restrict__ rowwt,
                                                  float* __restrict__ out) {
  const int NS = FDIM / BK;  // 16
  int e = blockIdx.z;
  int rbeg = off[e];
  int rows = off[e + 1] - rbeg;
  int m0 = blockIdx.y * BM;
  if (m0 >= rows) return;
  int n0 = blockIdx.x * BN;

  __shared__ ushort Ah[2][BM * BK];
  __shared__ ushort Al[2][BM * BK];
  __shared__ float  Bf[3][BN * BK];

  int tid = threadIdx.x;
  int lane = tid & 63;
  int w = tid >> 6;

  int ldsA0 = w * 2048, ldsA1 = w * 2048 + 1024;
  int ldsB0 = ldsA0, ldsB1 = ldsA1;
  const ushort *gA00, *gA10, *gA01, *gA11;
  {
    int p0 = ldsA0 + lane * 16, p1 = ldsA1 + lane * 16;
    int q0 = inv_swz64(p0), q1 = inv_swz64(p1);
    int r0 = m0 + (q0 >> 6); r0 = r0 < rows ? r0 : rows - 1;
    int r1 = m0 + (q1 >> 6); r1 = r1 < rows ? r1 : rows - 1;
    size_t b0 = (size_t)(rbeg + r0) * FDIM + ((q0 & 63) >> 1);
    size_t b1 = (size_t)(rbeg + r1) * FDIM + ((q1 & 63) >> 1);
    gA00 = ahi + b0; gA10 = ahi + b1;
    gA01 = alo + b0; gA11 = alo + b1;
  }
  const float *gB0, *gB1;
  {
    int p0 = ldsB0 + lane * 16, p1 = ldsB1 + lane * 16;
    int r0 = p0 >> 7, r1 = p1 >> 7;
    int c0 = ((p0 & 127) ^ ((r0 & 7) << 4)) >> 2;
    int c1 = ((p1 & 127) ^ ((r1 & 7) << 4)) >> 2;
    gB0 = w2 + ((size_t)e * DIM + (n0 + r0)) * FDIM + c0;
    gB1 = w2 + ((size_t)e * DIM + (n0 + r1)) * FDIM + c1;
  }

  MOE_READ_OFFSETS()

  f32x4 acc[4][2];
#pragma unroll
  for (int a = 0; a < 4; ++a)
#pragma unroll
    for (int b = 0; b < 2; ++b) acc[a][b] = {0.f, 0.f, 0.f, 0.f};

  ushort *ahc = Ah[0], *ahn = Ah[1];
  ushort *alc = Al[0], *aln = Al[1];
  float  *bfc = Bf[0], *bf1 = Bf[1], *bfn = Bf[2];

  MOE_PIPE_LOOP(NS);

#pragma unroll
  for (int fm = 0; fm < 4; ++fm) {
    int rloc = wm + fm * 16 + lk * 4;
#pragma unroll
    for (int j = 0; j < 4; ++j) {
      int row = rloc + j;
      if (m0 + row < rows) {
        int idx = rbeg + m0 + row;
        int tok = rowtok[idx];
        float wgt = rowwt[idx];
        float* orow = out + (size_t)tok * DIM + n0;
#pragma unroll
        for (int fn = 0; fn < 2; ++fn)
          atomicAdd(orow + wn + fn * 16 + lr, wgt * acc[fm][fn][j]);
      }
    }
  }
}

// ---------------------------------------------------------------------------
extern "C" void kernel_launch(void* const* d_in, const int* in_sizes, int n_in,
                              void* d_out, int out_size, void* d_ws, size_t ws_size,
                              hipStream_t stream) {
  const float* x   = (const float*)d_in[0];
  const float* wg  = (const float*)d_in[1];
  const float* w13 = (const float*)d_in[2];
  const float* w2  = (const float*)d_in[3];
  float* out = (float*)d_out;

  char* ws = (char*)d_ws;
  int*   cnt    = (int*)(ws + 0);
  int*   cnt2   = (int*)(ws + 64);
  int*   off    = (int*)(ws + 128);
  int*   sel    = (int*)(ws + 1024);
  float* wt     = (float*)(ws + 1024 + 16384);
  int*   rowtok = (int*)(ws + 1024 + 32768);
  float* rowwt  = (float*)(ws + 1024 + 49152);
  size_t o = 128 * 1024;
  ushort* xhi = (ushort*)(ws + o); o += (size_t)T_TOK * DIM * 2;
  ushort* xlo = (ushort*)(ws + o); o += (size_t)T_TOK * DIM * 2;
  float*  H   = (float*)(ws + o);  o += (size_t)T_TOK * TOPK * 2 * FDIM * 4;
  ushort* ahi = (ushort*)(ws + o); o += (size_t)T_TOK * TOPK * FDIM * 2;
  ushort* alo = (ushort*)(ws + o); o += (size_t)T_TOK * TOPK * FDIM * 2;
  // total ws use ≈ 32.1 MB

  hipMemsetAsync(ws, 0, 256, stream);                              // cnt, cnt2
  hipMemsetAsync(d_out, 0, (size_t)out_size * sizeof(float), stream);

  router_k<<<T_TOK, 64, 0, stream>>>(x, wg, sel, wt);
  xsplit_k<<<(T_TOK * DIM) / 1024, 256, 0, stream>>>(x, xhi, xlo);
  hist_k<<<(T_TOK * TOPK) / 256, 256, 0, stream>>>(sel, cnt);
  offsets_k<<<1, 64, 0, stream>>>(cnt, off);
  fill_k<<<(T_TOK * TOPK) / 256, 256, 0, stream>>>(sel, wt, off, cnt2, rowtok, rowwt);

  dim3 g1(2 * FDIM / BN, T_TOK / BM, NEXP);  // (16,16,16), most blocks early-exit
  gemm1_k<<<g1, 256, 0, stream>>>(xhi, xlo, w13, off, rowtok, H);

  act_k<<<(T_TOK * TOPK * FDIM) / 1024, 256, 0, stream>>>(H, ahi, alo);

  dim3 g2(DIM / BN, T_TOK / BM, NEXP);       // (16,16,16)
  gemm2_k<<<g2, 256, 0, stream>>>(ahi, alo, w2, off, rowtok, rowwt, out);
}